// Round 1
// baseline (2113.852 us; speedup 1.0000x reference)
//
#include <hip/hip_runtime.h>

#define TT 215
#define BB 256

// ---------------------------------------------------------------- x = (src[:,:,:36] @ W_enc.T + b) * 6
__global__ void k_encode_x(const float* __restrict__ src, const float* __restrict__ W,
                           const float* __restrict__ bias, float* __restrict__ x) {
    int idx = blockIdx.x * blockDim.x + threadIdx.x;
    if (idx >= TT * BB * 36) return;
    int o = idx % 36, tb = idx / 36;
    const float* s = src + (size_t)tb * 72;
    const float* w = W + o * 36;
    float acc = bias[o];
#pragma unroll
    for (int i = 0; i < 36; ++i) acc = fmaf(s[i], w[i], acc);
    x[idx] = acc * 6.0f;
}

// ---------------------------------------------------------------- h[:, :, :36] = x@Wskip.T+b ; h[:, :, 36:] = pe
__global__ void k_skip_pe(const float* __restrict__ x, const float* __restrict__ times,
                          const float* __restrict__ W, const float* __restrict__ bias,
                          float* __restrict__ h) {
    int idx = blockIdx.x * blockDim.x + threadIdx.x;
    if (idx >= TT * BB * 72) return;
    int o = idx % 72, tb = idx / 72;
    float val;
    if (o < 36) {
        const float* xr = x + (size_t)tb * 36;
        const float* w = W + o * 36;
        val = bias[o];
#pragma unroll
        for (int i = 0; i < 36; ++i) val = fmaf(xr[i], w[i], val);
    } else {
        int d = o - 36;
        int kk = (d < 18) ? d : (d - 18);
        double ts = pow(215.0, (double)kk / 17.0);  // matches np float64 215**linspace
        float scl = times[tb] / (float)ts;
        val = (d < 18) ? sinf(scl) : cosf(scl);
    }
    h[idx] = val;
}

// ---------------------------------------------------------------- q,k,v over first 36 time steps
__global__ void k_graph_qkv(const float* __restrict__ x,
                            const float* __restrict__ Wq, const float* __restrict__ bq,
                            const float* __restrict__ Wk, const float* __restrict__ bk,
                            const float* __restrict__ Wv, const float* __restrict__ bv,
                            float* __restrict__ qg, float* __restrict__ kg, float* __restrict__ vg) {
    int idx = blockIdx.x * blockDim.x + threadIdx.x;
    if (idx >= 36 * BB * 36) return;
    int o = idx % 36, tb = idx / 36;  // tb = t*BB + b, t<36; same layout as x
    const float* xr = x + (size_t)tb * 36;
    float aq = bq[o], ak = bk[o], av = bv[o];
#pragma unroll
    for (int i = 0; i < 36; ++i) {
        float xi = xr[i];
        aq = fmaf(xi, Wq[o * 36 + i], aq);
        ak = fmaf(xi, Wk[o * 36 + i], ak);
        av = fmaf(xi, Wv[o * 36 + i], av);
    }
    qg[idx] = aq; kg[idx] = ak; vg[idx] = av;
}

// ---------------------------------------------------------------- graph attention per batch; h[:36,:,:36] += msg
__global__ void k_graph_attn(const float* __restrict__ qg, const float* __restrict__ kg,
                             const float* __restrict__ vg, float* __restrict__ h,
                             float* __restrict__ Abuf, float* __restrict__ sqv) {
    __shared__ float q[1296], k[1296], v[1296], A[1296];
    __shared__ float red[128];
    int b = blockIdx.x, tid = threadIdx.x;
    for (int i = tid; i < 1296; i += 128) {
        int t = i / 36, e = i % 36;
        int g = (t * BB + b) * 36 + e;
        q[i] = qg[g]; k[i] = kg[g]; v[i] = vg[g];
    }
    __syncthreads();
    for (int i = tid; i < 1296; i += 128) {
        int r = i / 36, c = i % 36;
        float a = 0.f;
#pragma unroll
        for (int e = 0; e < 36; ++e) a = fmaf(q[r * 36 + e], k[c * 36 + e], a);
        A[i] = a * (1.0f / 6.0f);
    }
    __syncthreads();
    if (tid < 36) {  // softmax over j for row tid
        float m = -1e30f;
        for (int j = 0; j < 36; ++j) m = fmaxf(m, A[tid * 36 + j]);
        float s = 0.f;
        for (int j = 0; j < 36; ++j) { float e = expf(A[tid * 36 + j] - m); A[tid * 36 + j] = e; s += e; }
        float inv = 1.0f / s;
        for (int j = 0; j < 36; ++j) A[tid * 36 + j] *= inv;
    }
    __syncthreads();
    float lsq = 0.f;
    for (int i = tid; i < 1296; i += 128) {
        float a = A[i];
        Abuf[(size_t)b * 1296 + i] = a;
        lsq = fmaf(a, a, lsq);
        int r = i / 36, e = i % 36;
        float m = 0.f;
#pragma unroll
        for (int j = 0; j < 36; ++j) m = fmaf(A[r * 36 + j], v[j * 36 + e], m);
        h[((size_t)r * BB + b) * 72 + e] += m;
    }
    red[tid] = lsq;
    __syncthreads();
    for (int s = 64; s > 0; s >>= 1) { if (tid < s) red[tid] += red[tid + s]; __syncthreads(); }
    if (tid == 0) sqv[b] = red[0];
}

// ---------------------------------------------------------------- Gram row + per-row distance partial sum
__global__ void k_gram(const float* __restrict__ Abuf, const float* __restrict__ sqv,
                       float* __restrict__ rowsum) {
    __shared__ float Arow[1296];
    __shared__ float red[256];
    int b1 = blockIdx.x, tid = threadIdx.x;
    for (int i = tid; i < 1296; i += 256) Arow[i] = Abuf[(size_t)b1 * 1296 + i];
    __syncthreads();
    int b2 = tid;
    const float* a2 = Abuf + (size_t)b2 * 1296;
    float dot = 0.f;
    for (int e = 0; e < 1296; ++e) dot = fmaf(Arow[e], a2[e], dot);
    float d2 = fmaxf(sqv[b1] + sqv[b2] - 2.0f * dot, 0.0f);
    red[tid] = (d2 > 0.0f) ? sqrtf(d2) : 0.0f;
    __syncthreads();
    for (int s = 128; s > 0; s >>= 1) { if (tid < s) red[tid] += red[tid + s]; __syncthreads(); }
    if (tid == 0) rowsum[b1] = red[0];
}

// ---------------------------------------------------------------- qkv = h @ W_in.T + b_in  ([T,B,216])
__global__ void k_qkv(const float* __restrict__ h, const float* __restrict__ W,
                      const float* __restrict__ bias, float* __restrict__ qkv) {
    int idx = blockIdx.x * blockDim.x + threadIdx.x;
    if (idx >= TT * BB * 216) return;
    int o = idx % 216, tb = idx / 216;
    const float* hr = h + (size_t)tb * 72;
    const float* w = W + o * 72;
    float acc = bias[o];
#pragma unroll
    for (int i = 0; i < 72; ++i) acc = fmaf(hr[i], w[i], acc);
    qkv[idx] = acc;
}

// ---------------------------------------------------------------- masked MHA, block = (b, head), thread = query row
__global__ void k_attn(const float* __restrict__ qkv, const int* __restrict__ lengths,
                       float* __restrict__ ctx) {
    __shared__ float Ks[TT * 18];
    __shared__ float Vs[TT * 18];
    int b = blockIdx.x & (BB - 1);
    int hh = blockIdx.x >> 8;
    int tid = threadIdx.x;
    int len = lengths[b];
    for (int i = tid; i < TT * 18; i += 256) {
        int s = i / 18, d = i % 18;
        size_t base = ((size_t)s * BB + b) * 216;
        Ks[i] = qkv[base + 72 + hh * 18 + d];
        Vs[i] = qkv[base + 144 + hh * 18 + d];
    }
    __syncthreads();
    int t = tid;
    if (t >= TT) return;
    float q[18];
    size_t qb = ((size_t)t * BB + b) * 216 + hh * 18;
#pragma unroll
    for (int d = 0; d < 18; ++d) q[d] = qkv[qb + d];
    const float scale = 0.23570226039551587f;  // 1/sqrt(18)
    float m = -1e30f, l = 0.f;
    float acc[18];
#pragma unroll
    for (int d = 0; d < 18; ++d) acc[d] = 0.f;
    for (int s = 0; s < len; ++s) {
        float sc = 0.f;
#pragma unroll
        for (int d = 0; d < 18; ++d) sc = fmaf(q[d], Ks[s * 18 + d], sc);
        sc *= scale;
        float mn = fmaxf(m, sc);
        float alpha = expf(m - mn);
        float p = expf(sc - mn);
        l = l * alpha + p;
#pragma unroll
        for (int d = 0; d < 18; ++d) acc[d] = fmaf(acc[d], alpha, p * Vs[s * 18 + d]);
        m = mn;
    }
    float inv = 1.0f / l;
    size_t cb = ((size_t)t * BB + b) * 72 + hh * 18;
#pragma unroll
    for (int d = 0; d < 18; ++d) ctx[cb + d] = acc[d] * inv;
}

// ---------------------------------------------------------------- h = LN(h + ctx @ Wout.T + bout)
__global__ void k_outln(const float* __restrict__ ctx, const float* __restrict__ W,
                        const float* __restrict__ bias, const float* __restrict__ g,
                        const float* __restrict__ beta, float* __restrict__ h) {
    __shared__ float c[72];
    __shared__ float vals[72];
    __shared__ float mu_s, rstd_s;
    int tb = blockIdx.x, tid = threadIdx.x;
    if (tid < 72) c[tid] = ctx[(size_t)tb * 72 + tid];
    __syncthreads();
    float val = 0.f;
    if (tid < 72) {
        const float* w = W + tid * 72;
        val = bias[tid];
#pragma unroll
        for (int i = 0; i < 72; ++i) val = fmaf(c[i], w[i], val);
        val += h[(size_t)tb * 72 + tid];
        vals[tid] = val;
    }
    __syncthreads();
    if (tid == 0) {
        float s = 0.f;
        for (int i = 0; i < 72; ++i) s += vals[i];
        float mu = s / 72.0f;
        float v = 0.f;
        for (int i = 0; i < 72; ++i) { float d = vals[i] - mu; v = fmaf(d, d, v); }
        mu_s = mu;
        rstd_s = 1.0f / sqrtf(v / 72.0f + 1e-5f);
    }
    __syncthreads();
    if (tid < 72) h[(size_t)tb * 72 + tid] = (val - mu_s) * rstd_s * g[tid] + beta[tid];
}

// ---------------------------------------------------------------- h = LN(h + relu(h@ff1.T+b1)@ff2.T+b2)
__global__ void k_ffln(const float* __restrict__ ff1, const float* __restrict__ b1,
                       const float* __restrict__ ff2, const float* __restrict__ b2,
                       const float* __restrict__ g, const float* __restrict__ beta,
                       float* __restrict__ h) {
    __shared__ float hr[72];
    __shared__ float hid[128];
    __shared__ float vals[72];
    __shared__ float mu_s, rstd_s;
    int tb = blockIdx.x, tid = threadIdx.x;
    if (tid < 72) hr[tid] = h[(size_t)tb * 72 + tid];
    __syncthreads();
    {
        float a = b1[tid];
        const float* w = ff1 + tid * 72;
#pragma unroll
        for (int i = 0; i < 72; ++i) a = fmaf(hr[i], w[i], a);
        hid[tid] = fmaxf(a, 0.f);
    }
    __syncthreads();
    float val = 0.f;
    if (tid < 72) {
        float a = b2[tid];
        const float* w = ff2 + tid * 128;
#pragma unroll
        for (int i = 0; i < 128; ++i) a = fmaf(hid[i], w[i], a);
        val = a + hr[tid];
        vals[tid] = val;
    }
    __syncthreads();
    if (tid == 0) {
        float s = 0.f;
        for (int i = 0; i < 72; ++i) s += vals[i];
        float mu = s / 72.0f;
        float v = 0.f;
        for (int i = 0; i < 72; ++i) { float d = vals[i] - mu; v = fmaf(d, d, v); }
        mu_s = mu;
        rstd_s = 1.0f / sqrtf(v / 72.0f + 1e-5f);
    }
    __syncthreads();
    if (tid < 72) h[(size_t)tb * 72 + tid] = (val - mu_s) * rstd_s * g[tid] + beta[tid];
}

// ---------------------------------------------------------------- masked mean-pool + static emb + 2-layer MLP
__global__ void k_head(const float* __restrict__ h, const int* __restrict__ lengths,
                       const float* __restrict__ statics, const float* __restrict__ W_emb,
                       const float* __restrict__ b_emb, const float* __restrict__ w1,
                       const float* __restrict__ bb1, const float* __restrict__ w2,
                       const float* __restrict__ bb2, float* __restrict__ out) {
    __shared__ float feat[108];
    __shared__ float hid[108];
    __shared__ float st[9];
    int b = blockIdx.x, tid = threadIdx.x;
    int len = lengths[b];
    if (tid < 9) st[tid] = statics[b * 9 + tid];
    if (tid < 72) {
        float s = 0.f;
        for (int t = 0; t < len; ++t) s += h[((size_t)t * BB + b) * 72 + tid];
        feat[tid] = s / ((float)len + 1.0f);
    }
    __syncthreads();
    if (tid < 36) {
        float a = b_emb[tid];
#pragma unroll
        for (int i = 0; i < 9; ++i) a = fmaf(st[i], W_emb[tid * 9 + i], a);
        feat[72 + tid] = a;
    }
    __syncthreads();
    if (tid < 108) {
        float a = bb1[tid];
        for (int i = 0; i < 108; ++i) a = fmaf(feat[i], w1[tid * 108 + i], a);
        hid[tid] = fmaxf(a, 0.f);
    }
    __syncthreads();
    if (tid < 2) {
        float a = bb2[tid];
        for (int i = 0; i < 108; ++i) a = fmaf(hid[i], w2[tid * 108 + i], a);
        out[b * 2 + tid] = a;
    }
}

// ---------------------------------------------------------------- final distance reduce
__global__ void k_dist(const float* __restrict__ rowsum, float* __restrict__ out) {
    __shared__ float red[256];
    int tid = threadIdx.x;
    red[tid] = rowsum[tid];
    __syncthreads();
    for (int s = 128; s > 0; s >>= 1) { if (tid < s) red[tid] += red[tid + s]; __syncthreads(); }
    if (tid == 0) out[2 * BB] = red[0] / 65536.0f;
}

extern "C" void kernel_launch(void* const* d_in, const int* in_sizes, int n_in,
                              void* d_out, int out_size, void* d_ws, size_t ws_size,
                              hipStream_t stream) {
    const float* src     = (const float*)d_in[0];
    const float* statics = (const float*)d_in[1];
    const float* times   = (const float*)d_in[2];
    const int*   lengths = (const int*)d_in[3];
    const float* W_enc = (const float*)d_in[4];  const float* b_enc = (const float*)d_in[5];
    const float* W_emb = (const float*)d_in[6];  const float* b_emb = (const float*)d_in[7];
    const float* Wq = (const float*)d_in[8];     const float* bq = (const float*)d_in[9];
    const float* Wk = (const float*)d_in[10];    const float* bk = (const float*)d_in[11];
    const float* Wv = (const float*)d_in[12];    const float* bv = (const float*)d_in[13];
    const float* Wskip = (const float*)d_in[14]; const float* bskip = (const float*)d_in[15];
    const float* enc_in_w = (const float*)d_in[16];  const float* enc_in_b = (const float*)d_in[17];
    const float* enc_out_w = (const float*)d_in[18]; const float* enc_out_b = (const float*)d_in[19];
    const float* ff1_w = (const float*)d_in[20]; const float* ff1_b = (const float*)d_in[21];
    const float* ff2_w = (const float*)d_in[22]; const float* ff2_b = (const float*)d_in[23];
    const float* ln1_g = (const float*)d_in[24]; const float* ln1_b = (const float*)d_in[25];
    const float* ln2_g = (const float*)d_in[26]; const float* ln2_b = (const float*)d_in[27];
    const float* w1 = (const float*)d_in[28];    const float* bb1 = (const float*)d_in[29];
    const float* w2 = (const float*)d_in[30];    const float* bb2 = (const float*)d_in[31];
    float* out = (float*)d_out;

    float* p = (float*)d_ws;
    float* x    = p; p += (size_t)TT * BB * 36;
    float* h    = p; p += (size_t)TT * BB * 72;
    float* qkv  = p; p += (size_t)TT * BB * 216;
    float* ctx  = p; p += (size_t)TT * BB * 72;
    float* qg   = p; p += (size_t)36 * BB * 36;
    float* kg   = p; p += (size_t)36 * BB * 36;
    float* vg   = p; p += (size_t)36 * BB * 36;
    float* Abuf = p; p += (size_t)BB * 1296;
    float* sqv  = p; p += BB;
    float* rsum = p; p += BB;

    k_encode_x<<<(TT * BB * 36) / 256, 256, 0, stream>>>(src, W_enc, b_enc, x);
    k_skip_pe<<<(TT * BB * 72) / 256, 256, 0, stream>>>(x, times, Wskip, bskip, h);
    k_graph_qkv<<<(36 * BB * 36) / 256, 256, 0, stream>>>(x, Wq, bq, Wk, bk, Wv, bv, qg, kg, vg);
    k_graph_attn<<<BB, 128, 0, stream>>>(qg, kg, vg, h, Abuf, sqv);
    k_gram<<<BB, 256, 0, stream>>>(Abuf, sqv, rsum);
    for (int l = 0; l < 2; ++l) {
        k_qkv<<<(TT * BB * 216) / 256, 256, 0, stream>>>(h, enc_in_w + l * 216 * 72,
                                                         enc_in_b + l * 216, qkv);
        k_attn<<<BB * 4, 256, 0, stream>>>(qkv, lengths, ctx);
        k_outln<<<TT * BB, 128, 0, stream>>>(ctx, enc_out_w + l * 72 * 72, enc_out_b + l * 72,
                                             ln1_g + l * 72, ln1_b + l * 72, h);
        k_ffln<<<TT * BB, 128, 0, stream>>>(ff1_w + l * 128 * 72, ff1_b + l * 128,
                                            ff2_w + l * 72 * 128, ff2_b + l * 72,
                                            ln2_g + l * 72, ln2_b + l * 72, h);
    }
    k_head<<<BB, 128, 0, stream>>>(h, lengths, statics, W_emb, b_emb, w1, bb1, w2, bb2, out);
    k_dist<<<1, 256, 0, stream>>>(rsum, out);
}

// Round 2
// 1117.406 us; speedup vs baseline: 1.8917x; 1.8917x over previous
//
#include <hip/hip_runtime.h>

#define TT 215
#define BB 256
#define ROWS (TT * BB)  // 55040 = 215 blocks x 256 threads exactly

// ---------------------------------------------------------------- one-shot prep: weight transposes + timescales
__global__ void k_prep(const float* __restrict__ W_enc, const float* __restrict__ Wskip,
                       const float* __restrict__ Wq, const float* __restrict__ Wk,
                       const float* __restrict__ Wv, const float* __restrict__ enc_out_w,
                       const float* __restrict__ ff2_w,
                       float* __restrict__ T_enc, float* __restrict__ T_skip,
                       float* __restrict__ Tq, float* __restrict__ Tk, float* __restrict__ Tv,
                       float* __restrict__ T_out, float* __restrict__ T_ff2,
                       float* __restrict__ ts) {
    int g = blockIdx.x * 256 + threadIdx.x;
    if (g < 18) ts[g] = (float)pow(215.0, (double)g / 17.0);  // matches np float64 215**linspace
    if (g < 1296) {
        int r = g / 36, c = g % 36;
        T_enc[c * 36 + r] = W_enc[g];
        T_skip[c * 36 + r] = Wskip[g];
        Tq[c * 36 + r] = Wq[g];
        Tk[c * 36 + r] = Wk[g];
        Tv[c * 36 + r] = Wv[g];
    }
    if (g < 2 * 5184) {  // enc_out_w [2][72][72] -> [2][i][o]
        int l = g / 5184, e = g % 5184;
        int r = e / 72, c = e % 72;
        T_out[l * 5184 + c * 72 + r] = enc_out_w[g];
    }
    if (g < 2 * 9216) {  // ff2 [2][72][128] -> [2][j][o]
        int l = g / 9216, e = g % 9216;
        int o = e / 128, j = e % 128;
        T_ff2[l * 9216 + j * 72 + o] = ff2_w[g];
    }
}

// ---------------------------------------------------------------- x = (src[:,:,:36] @ W_enc.T + b) * 6 ; thread = row
__global__ __launch_bounds__(256) void k_encode(const float* __restrict__ src,
                                                const float* __restrict__ TW,
                                                const float* __restrict__ bias,
                                                float* __restrict__ x) {
    int row = blockIdx.x * 256 + threadIdx.x;
    float acc[36];
#pragma unroll
    for (int o = 0; o < 36; ++o) acc[o] = bias[o];
    const float* s = src + (size_t)row * 72;
    for (int i = 0; i < 36; ++i) {
        float si = s[i];
#pragma unroll
        for (int o = 0; o < 36; ++o) acc[o] = fmaf(si, TW[i * 36 + o], acc[o]);
    }
    float4* xv = (float4*)(x + (size_t)row * 36);
#pragma unroll
    for (int k = 0; k < 9; ++k)
        xv[k] = make_float4(acc[4 * k] * 6.f, acc[4 * k + 1] * 6.f, acc[4 * k + 2] * 6.f, acc[4 * k + 3] * 6.f);
}

// ---------------------------------------------------------------- h[:,:, :36] = x@Wskip.T+b ; h[:,:,36:] = pe
__global__ __launch_bounds__(256) void k_skip_pe(const float* __restrict__ x,
                                                 const float* __restrict__ times,
                                                 const float* __restrict__ TW,
                                                 const float* __restrict__ bias,
                                                 const float* __restrict__ ts,
                                                 float* __restrict__ h) {
    int row = blockIdx.x * 256 + threadIdx.x;
    float acc[36];
#pragma unroll
    for (int o = 0; o < 36; ++o) acc[o] = bias[o];
    const float* xr = x + (size_t)row * 36;
    for (int i = 0; i < 36; ++i) {
        float xi = xr[i];
#pragma unroll
        for (int o = 0; o < 36; ++o) acc[o] = fmaf(xi, TW[i * 36 + o], acc[o]);
    }
    float* hr = h + (size_t)row * 72;
    float4* hv = (float4*)hr;
#pragma unroll
    for (int k = 0; k < 9; ++k)
        hv[k] = make_float4(acc[4 * k], acc[4 * k + 1], acc[4 * k + 2], acc[4 * k + 3]);
    float t = times[row];
#pragma unroll
    for (int d = 0; d < 18; ++d) {
        float sc = t / ts[d];
        hr[36 + d] = sinf(sc);
        hr[54 + d] = cosf(sc);
    }
}

// ---------------------------------------------------------------- graph q,k,v over first 36 time steps; thread = row
__global__ __launch_bounds__(256, 1) void k_graph_qkv(const float* __restrict__ x,
                                                      const float* __restrict__ Tq, const float* __restrict__ bq,
                                                      const float* __restrict__ Tk, const float* __restrict__ bk,
                                                      const float* __restrict__ Tv, const float* __restrict__ bv,
                                                      float* __restrict__ qg, float* __restrict__ kg,
                                                      float* __restrict__ vg) {
    int row = blockIdx.x * 256 + threadIdx.x;  // < 9216
    float aq[36], ak[36], av[36];
#pragma unroll
    for (int o = 0; o < 36; ++o) { aq[o] = bq[o]; ak[o] = bk[o]; av[o] = bv[o]; }
    const float* xr = x + (size_t)row * 36;
    for (int i = 0; i < 36; ++i) {
        float xi = xr[i];
#pragma unroll
        for (int o = 0; o < 36; ++o) {
            aq[o] = fmaf(xi, Tq[i * 36 + o], aq[o]);
            ak[o] = fmaf(xi, Tk[i * 36 + o], ak[o]);
            av[o] = fmaf(xi, Tv[i * 36 + o], av[o]);
        }
    }
    float4* qv = (float4*)(qg + (size_t)row * 36);
    float4* kv = (float4*)(kg + (size_t)row * 36);
    float4* vv = (float4*)(vg + (size_t)row * 36);
#pragma unroll
    for (int k = 0; k < 9; ++k) {
        qv[k] = make_float4(aq[4 * k], aq[4 * k + 1], aq[4 * k + 2], aq[4 * k + 3]);
        kv[k] = make_float4(ak[4 * k], ak[4 * k + 1], ak[4 * k + 2], ak[4 * k + 3]);
        vv[k] = make_float4(av[4 * k], av[4 * k + 1], av[4 * k + 2], av[4 * k + 3]);
    }
}

// ---------------------------------------------------------------- graph attention per batch; h[:36,:,:36] += msg
__global__ void k_graph_attn(const float* __restrict__ qg, const float* __restrict__ kg,
                             const float* __restrict__ vg, float* __restrict__ h,
                             float* __restrict__ Abuf, float* __restrict__ sqv) {
    __shared__ float q[1296], k[1296], v[1296], A[1296];
    __shared__ float red[128];
    int b = blockIdx.x, tid = threadIdx.x;
    for (int i = tid; i < 1296; i += 128) {
        int t = i / 36, e = i % 36;
        int g = (t * BB + b) * 36 + e;
        q[i] = qg[g]; k[i] = kg[g]; v[i] = vg[g];
    }
    __syncthreads();
    for (int i = tid; i < 1296; i += 128) {
        int r = i / 36, c = i % 36;
        float a = 0.f;
#pragma unroll
        for (int e = 0; e < 36; ++e) a = fmaf(q[r * 36 + e], k[c * 36 + e], a);
        A[i] = a * (1.0f / 6.0f);
    }
    __syncthreads();
    if (tid < 36) {
        float m = -1e30f;
        for (int j = 0; j < 36; ++j) m = fmaxf(m, A[tid * 36 + j]);
        float s = 0.f;
        for (int j = 0; j < 36; ++j) { float e = expf(A[tid * 36 + j] - m); A[tid * 36 + j] = e; s += e; }
        float inv = 1.0f / s;
        for (int j = 0; j < 36; ++j) A[tid * 36 + j] *= inv;
    }
    __syncthreads();
    float lsq = 0.f;
    for (int i = tid; i < 1296; i += 128) {
        float a = A[i];
        Abuf[(size_t)b * 1296 + i] = a;
        lsq = fmaf(a, a, lsq);
        int r = i / 36, e = i % 36;
        float m = 0.f;
#pragma unroll
        for (int j = 0; j < 36; ++j) m = fmaf(A[r * 36 + j], v[j * 36 + e], m);
        h[((size_t)r * BB + b) * 72 + e] += m;
    }
    red[tid] = lsq;
    __syncthreads();
    for (int s = 64; s > 0; s >>= 1) { if (tid < s) red[tid] += red[tid + s]; __syncthreads(); }
    if (tid == 0) sqv[b] = red[0];
}

// ---------------------------------------------------------------- Gram row + per-row distance partial sum
__global__ void k_gram(const float* __restrict__ Abuf, const float* __restrict__ sqv,
                       float* __restrict__ rowsum) {
    __shared__ float Arow[1296];
    __shared__ float red[256];
    int b1 = blockIdx.x, tid = threadIdx.x;
    for (int i = tid; i < 1296; i += 256) Arow[i] = Abuf[(size_t)b1 * 1296 + i];
    __syncthreads();
    int b2 = tid;
    const float* a2 = Abuf + (size_t)b2 * 1296;
    float dot = 0.f;
    for (int e = 0; e < 1296; ++e) dot = fmaf(Arow[e], a2[e], dot);
    float d2 = fmaxf(sqv[b1] + sqv[b2] - 2.0f * dot, 0.0f);
    red[tid] = (d2 > 0.0f) ? sqrtf(d2) : 0.0f;
    __syncthreads();
    for (int s = 128; s > 0; s >>= 1) { if (tid < s) red[tid] += red[tid + s]; __syncthreads(); }
    if (tid == 0) rowsum[b1] = red[0];
}

// ---------------------------------------------------------------- qkv = h @ W_in.T + b_in ; thread = row
__global__ __launch_bounds__(256, 1) void k_qkv(const float* __restrict__ h, const float* __restrict__ W,
                                                const float* __restrict__ bias, float* __restrict__ qkv) {
    int row = blockIdx.x * 256 + threadIdx.x;
    float hr[72];
    const float4* hv = (const float4*)(h + (size_t)row * 72);
#pragma unroll
    for (int k = 0; k < 18; ++k) {
        float4 v = hv[k];
        hr[4 * k] = v.x; hr[4 * k + 1] = v.y; hr[4 * k + 2] = v.z; hr[4 * k + 3] = v.w;
    }
    float* qr = qkv + (size_t)row * 216;
    for (int j0 = 0; j0 < 216; j0 += 8) {
        float a[8];
#pragma unroll
        for (int k = 0; k < 8; ++k) {
            float acc = bias[j0 + k];
            const float* w = W + (size_t)(j0 + k) * 72;
#pragma unroll
            for (int i = 0; i < 72; ++i) acc = fmaf(hr[i], w[i], acc);
            a[k] = acc;
        }
        float4* qv = (float4*)(qr + j0);
        qv[0] = make_float4(a[0], a[1], a[2], a[3]);
        qv[1] = make_float4(a[4], a[5], a[6], a[7]);
    }
}

// ---------------------------------------------------------------- masked MHA, block = (b, head), thread = query row
__global__ __launch_bounds__(256) void k_attn(const float* __restrict__ qkv,
                                              const int* __restrict__ lengths,
                                              float* __restrict__ ctx) {
    __shared__ float Ks[TT * 20];
    __shared__ float Vs[TT * 20];
    int b = blockIdx.x & (BB - 1);
    int hh = blockIdx.x >> 8;
    int tid = threadIdx.x;
    int len = lengths[b];
    for (int i = tid; i < TT * 20; i += 256) {
        int s = i / 20, d = i % 20;
        float kk = 0.f, vv = 0.f;
        if (d < 18) {
            size_t base = ((size_t)s * BB + b) * 216 + hh * 18 + d;
            kk = qkv[base + 72];
            vv = qkv[base + 144];
        }
        Ks[i] = kk; Vs[i] = vv;
    }
    __syncthreads();
    if (tid >= TT) return;
    float q[20];
    q[18] = 0.f; q[19] = 0.f;
    {
        const float* qb = qkv + ((size_t)tid * BB + b) * 216 + hh * 18;
#pragma unroll
        for (int d = 0; d < 18; ++d) q[d] = qb[d];
    }
    const float scale = 0.23570226039551587f;  // 1/sqrt(18)
    float m = -1e30f, l = 0.f;
    float acc[20];
#pragma unroll
    for (int d = 0; d < 20; ++d) acc[d] = 0.f;
    for (int s = 0; s < len; ++s) {
        const float4* kp = (const float4*)(Ks + s * 20);  // broadcast b128 reads
        float sc = 0.f;
#pragma unroll
        for (int c = 0; c < 5; ++c) {
            float4 kv = kp[c];
            sc = fmaf(q[4 * c], kv.x, sc);
            sc = fmaf(q[4 * c + 1], kv.y, sc);
            sc = fmaf(q[4 * c + 2], kv.z, sc);
            sc = fmaf(q[4 * c + 3], kv.w, sc);
        }
        sc *= scale;
        float mn = fmaxf(m, sc);
        float alpha = __expf(m - mn);
        float p = __expf(sc - mn);
        l = l * alpha + p;
        const float4* vp = (const float4*)(Vs + s * 20);
#pragma unroll
        for (int c = 0; c < 5; ++c) {
            float4 vv = vp[c];
            acc[4 * c]     = fmaf(acc[4 * c], alpha, p * vv.x);
            acc[4 * c + 1] = fmaf(acc[4 * c + 1], alpha, p * vv.y);
            acc[4 * c + 2] = fmaf(acc[4 * c + 2], alpha, p * vv.z);
            acc[4 * c + 3] = fmaf(acc[4 * c + 3], alpha, p * vv.w);
        }
        m = mn;
    }
    float inv = 1.0f / l;
    float* cb = ctx + ((size_t)tid * BB + b) * 72 + hh * 18;
#pragma unroll
    for (int d = 0; d < 18; ++d) cb[d] = acc[d] * inv;
}

// ---------------------------------------------------------------- h = LN(h + ctx @ Wout.T + bout) ; thread = row
__global__ __launch_bounds__(256, 1) void k_outln(const float* __restrict__ ctx,
                                                  const float* __restrict__ TW,
                                                  const float* __restrict__ bias,
                                                  const float* __restrict__ g,
                                                  const float* __restrict__ beta,
                                                  float* __restrict__ h) {
    int row = blockIdx.x * 256 + threadIdx.x;
    float acc[72];
#pragma unroll
    for (int o = 0; o < 72; ++o) acc[o] = bias[o];
    const float* cr = ctx + (size_t)row * 72;
    for (int i = 0; i < 72; ++i) {
        float ci = cr[i];
#pragma unroll
        for (int o = 0; o < 72; ++o) acc[o] = fmaf(ci, TW[i * 72 + o], acc[o]);
    }
    float* hr = h + (size_t)row * 72;
#pragma unroll
    for (int o = 0; o < 72; ++o) acc[o] += hr[o];
    float s = 0.f;
#pragma unroll
    for (int o = 0; o < 72; ++o) s += acc[o];
    float mu = s / 72.0f;
    float var = 0.f;
#pragma unroll
    for (int o = 0; o < 72; ++o) { float d = acc[o] - mu; var = fmaf(d, d, var); }
    float rstd = 1.0f / sqrtf(var / 72.0f + 1e-5f);
    float4* hv = (float4*)hr;
#pragma unroll
    for (int k = 0; k < 18; ++k) {
        float4 o4;
        o4.x = (acc[4 * k] - mu) * rstd * g[4 * k] + beta[4 * k];
        o4.y = (acc[4 * k + 1] - mu) * rstd * g[4 * k + 1] + beta[4 * k + 1];
        o4.z = (acc[4 * k + 2] - mu) * rstd * g[4 * k + 2] + beta[4 * k + 2];
        o4.w = (acc[4 * k + 3] - mu) * rstd * g[4 * k + 3] + beta[4 * k + 3];
        hv[k] = o4;
    }
}

// ---------------------------------------------------------------- h = LN(h + relu(h@ff1.T+b1)@ff2.T+b2) ; thread = row
__global__ __launch_bounds__(256, 1) void k_ffln(const float* __restrict__ ff1,
                                                 const float* __restrict__ b1,
                                                 const float* __restrict__ Tff2,
                                                 const float* __restrict__ b2,
                                                 const float* __restrict__ g,
                                                 const float* __restrict__ beta,
                                                 float* __restrict__ h) {
    int row = blockIdx.x * 256 + threadIdx.x;
    float hr[72];
    float* hp = h + (size_t)row * 72;
    const float4* hv = (const float4*)hp;
#pragma unroll
    for (int k = 0; k < 18; ++k) {
        float4 v = hv[k];
        hr[4 * k] = v.x; hr[4 * k + 1] = v.y; hr[4 * k + 2] = v.z; hr[4 * k + 3] = v.w;
    }
    float acc[72];
#pragma unroll
    for (int o = 0; o < 72; ++o) acc[o] = b2[o];
    for (int j = 0; j < 128; ++j) {
        float a = b1[j];
        const float* w = ff1 + (size_t)j * 72;
#pragma unroll
        for (int i = 0; i < 72; ++i) a = fmaf(hr[i], w[i], a);
        a = fmaxf(a, 0.f);
        const float* wt = Tff2 + (size_t)j * 72;
#pragma unroll
        for (int o = 0; o < 72; ++o) acc[o] = fmaf(a, wt[o], acc[o]);
    }
#pragma unroll
    for (int o = 0; o < 72; ++o) acc[o] += hr[o];
    float s = 0.f;
#pragma unroll
    for (int o = 0; o < 72; ++o) s += acc[o];
    float mu = s / 72.0f;
    float var = 0.f;
#pragma unroll
    for (int o = 0; o < 72; ++o) { float d = acc[o] - mu; var = fmaf(d, d, var); }
    float rstd = 1.0f / sqrtf(var / 72.0f + 1e-5f);
    float4* ho = (float4*)hp;
#pragma unroll
    for (int k = 0; k < 18; ++k) {
        float4 o4;
        o4.x = (acc[4 * k] - mu) * rstd * g[4 * k] + beta[4 * k];
        o4.y = (acc[4 * k + 1] - mu) * rstd * g[4 * k + 1] + beta[4 * k + 1];
        o4.z = (acc[4 * k + 2] - mu) * rstd * g[4 * k + 2] + beta[4 * k + 2];
        o4.w = (acc[4 * k + 3] - mu) * rstd * g[4 * k + 3] + beta[4 * k + 3];
        ho[k] = o4;
    }
}

// ---------------------------------------------------------------- masked mean-pool + static emb + 2-layer MLP
__global__ void k_head(const float* __restrict__ h, const int* __restrict__ lengths,
                       const float* __restrict__ statics, const float* __restrict__ W_emb,
                       const float* __restrict__ b_emb, const float* __restrict__ w1,
                       const float* __restrict__ bb1, const float* __restrict__ w2,
                       const float* __restrict__ bb2, float* __restrict__ out) {
    __shared__ float feat[108];
    __shared__ float hid[108];
    __shared__ float st[9];
    int b = blockIdx.x, tid = threadIdx.x;
    int len = lengths[b];
    if (tid < 9) st[tid] = statics[b * 9 + tid];
    if (tid < 72) {
        float s = 0.f;
        for (int t = 0; t < len; ++t) s += h[((size_t)t * BB + b) * 72 + tid];
        feat[tid] = s / ((float)len + 1.0f);
    }
    __syncthreads();
    if (tid < 36) {
        float a = b_emb[tid];
#pragma unroll
        for (int i = 0; i < 9; ++i) a = fmaf(st[i], W_emb[tid * 9 + i], a);
        feat[72 + tid] = a;
    }
    __syncthreads();
    if (tid < 108) {
        float a = bb1[tid];
        for (int i = 0; i < 108; ++i) a = fmaf(feat[i], w1[tid * 108 + i], a);
        hid[tid] = fmaxf(a, 0.f);
    }
    __syncthreads();
    if (tid < 2) {
        float a = bb2[tid];
        for (int i = 0; i < 108; ++i) a = fmaf(hid[i], w2[tid * 108 + i], a);
        out[b * 2 + tid] = a;
    }
}

// ---------------------------------------------------------------- final distance reduce
__global__ void k_dist(const float* __restrict__ rowsum, float* __restrict__ out) {
    __shared__ float red[256];
    int tid = threadIdx.x;
    red[tid] = rowsum[tid];
    __syncthreads();
    for (int s = 128; s > 0; s >>= 1) { if (tid < s) red[tid] += red[tid + s]; __syncthreads(); }
    if (tid == 0) out[2 * BB] = red[0] / 65536.0f;
}

extern "C" void kernel_launch(void* const* d_in, const int* in_sizes, int n_in,
                              void* d_out, int out_size, void* d_ws, size_t ws_size,
                              hipStream_t stream) {
    const float* src     = (const float*)d_in[0];
    const float* statics = (const float*)d_in[1];
    const float* times   = (const float*)d_in[2];
    const int*   lengths = (const int*)d_in[3];
    const float* W_enc = (const float*)d_in[4];  const float* b_enc = (const float*)d_in[5];
    const float* W_emb = (const float*)d_in[6];  const float* b_emb = (const float*)d_in[7];
    const float* Wq = (const float*)d_in[8];     const float* bq = (const float*)d_in[9];
    const float* Wk = (const float*)d_in[10];    const float* bk = (const float*)d_in[11];
    const float* Wv = (const float*)d_in[12];    const float* bv = (const float*)d_in[13];
    const float* Wskip = (const float*)d_in[14]; const float* bskip = (const float*)d_in[15];
    const float* enc_in_w = (const float*)d_in[16];  const float* enc_in_b = (const float*)d_in[17];
    const float* enc_out_w = (const float*)d_in[18]; const float* enc_out_b = (const float*)d_in[19];
    const float* ff1_w = (const float*)d_in[20]; const float* ff1_b = (const float*)d_in[21];
    const float* ff2_w = (const float*)d_in[22]; const float* ff2_b = (const float*)d_in[23];
    const float* ln1_g = (const float*)d_in[24]; const float* ln1_b = (const float*)d_in[25];
    const float* ln2_g = (const float*)d_in[26]; const float* ln2_b = (const float*)d_in[27];
    const float* w1 = (const float*)d_in[28];    const float* bb1 = (const float*)d_in[29];
    const float* w2 = (const float*)d_in[30];    const float* bb2 = (const float*)d_in[31];
    float* out = (float*)d_out;

    float* p = (float*)d_ws;
    float* x    = p; p += (size_t)ROWS * 36;
    float* h    = p; p += (size_t)ROWS * 72;
    float* qkv  = p; p += (size_t)ROWS * 216;
    float* ctx  = p; p += (size_t)ROWS * 72;
    float* qg   = p; p += (size_t)36 * BB * 36;
    float* kg   = p; p += (size_t)36 * BB * 36;
    float* vg   = p; p += (size_t)36 * BB * 36;
    float* Abuf = p; p += (size_t)BB * 1296;
    float* sqv  = p; p += BB;
    float* rsum = p; p += BB;
    float* ts   = p; p += 32;
    float* T_enc  = p; p += 1296;
    float* T_skip = p; p += 1296;
    float* Tq     = p; p += 1296;
    float* Tk     = p; p += 1296;
    float* Tv     = p; p += 1296;
    float* T_out  = p; p += 2 * 5184;
    float* T_ff2  = p; p += 2 * 9216;

    k_prep<<<72, 256, 0, stream>>>(W_enc, Wskip, Wq, Wk, Wv, enc_out_w, ff2_w,
                                   T_enc, T_skip, Tq, Tk, Tv, T_out, T_ff2, ts);
    k_encode<<<TT, 256, 0, stream>>>(src, T_enc, b_enc, x);
    k_skip_pe<<<TT, 256, 0, stream>>>(x, times, T_skip, bskip, ts, h);
    k_graph_qkv<<<36, 256, 0, stream>>>(x, Tq, bq, Tk, bk, Tv, bv, qg, kg, vg);
    k_graph_attn<<<BB, 128, 0, stream>>>(qg, kg, vg, h, Abuf, sqv);
    k_gram<<<BB, 256, 0, stream>>>(Abuf, sqv, rsum);
    for (int l = 0; l < 2; ++l) {
        k_qkv<<<TT, 256, 0, stream>>>(h, enc_in_w + (size_t)l * 216 * 72, enc_in_b + l * 216, qkv);
        k_attn<<<BB * 4, 256, 0, stream>>>(qkv, lengths, ctx);
        k_outln<<<TT, 256, 0, stream>>>(ctx, T_out + (size_t)l * 5184, enc_out_b + l * 72,
                                        ln1_g + l * 72, ln1_b + l * 72, h);
        k_ffln<<<TT, 256, 0, stream>>>(ff1_w + (size_t)l * 128 * 72, ff1_b + l * 128,
                                       T_ff2 + (size_t)l * 9216, ff2_b + l * 72,
                                       ln2_g + l * 72, ln2_b + l * 72, h);
    }
    k_head<<<BB, 128, 0, stream>>>(h, lengths, statics, W_emb, b_emb, w1, bb1, w2, bb2, out);
    k_dist<<<1, 256, 0, stream>>>(rsum, out);
}